// Round 5
// baseline (259.362 us; speedup 1.0000x reference)
//
#include <hip/hip_runtime.h>
#include <math.h>

#define NBINS   64
#define GROUPS  16
#define HIDDEN  128
#define EPSF    1e-6f

// B=2, C=16, H=W=1024; 32 images of 1M floats; 32x32 tiles of 32x32 elems.
#define IMG_ELEMS   (1024*1024)
#define F4_PER_ROW  256          // 1024 cols / 4
#define NIMG        32           // B*C

typedef float nfloat4 __attribute__((ext_vector_type(4)));  // builtin-compatible

// ---------------------------------------------------------------------------
// Kernel 1: per image-row-chunk (32 rows): min/max partials + 32 tile sums.
// grid = NIMG*32 blocks, 256 threads.
// ---------------------------------------------------------------------------
__global__ __launch_bounds__(256) void k_stats(
        const float* __restrict__ x,
        float* __restrict__ blocksum,   // [NIMG][32][32] tile sums
        float* __restrict__ pmin,       // [NIMG*32]
        float* __restrict__ pmax)       // [NIMG*32]
{
    const int bid = blockIdx.x;
    const int bc  = bid >> 5;   // image
    const int i   = bid & 31;   // row-chunk (tile row)
    const int t   = threadIdx.x;
    const int lane = t & 63;
    const int wave = t >> 6;

    const float4* xin = (const float4*)(x + (size_t)bc * IMG_ELEMS);
    const int rowbase = (i * 32) * F4_PER_ROW;

    float s = 0.f, mn = INFINITY, mx = -INFINITY;
    #pragma unroll 4
    for (int r = 0; r < 32; ++r) {
        float4 v = xin[rowbase + r * F4_PER_ROW + t];
        s += (v.x + v.y) + (v.z + v.w);
        mn = fminf(mn, fminf(fminf(v.x, v.y), fminf(v.z, v.w)));
        mx = fmaxf(mx, fmaxf(fmaxf(v.x, v.y), fmaxf(v.z, v.w)));
    }

    // tile sums: 8 consecutive threads share tile j = t>>3 (within a wave)
    s += __shfl_xor(s, 4, 64);
    s += __shfl_xor(s, 2, 64);
    s += __shfl_xor(s, 1, 64);
    if ((t & 7) == 0)
        blocksum[bc * 1024 + i * 32 + (t >> 3)] = s;

    // block-wide min/max: wave shuffle reduce, then cross-wave via LDS
    #pragma unroll
    for (int st = 32; st > 0; st >>= 1) {
        mn = fminf(mn, __shfl_xor(mn, st, 64));
        mx = fmaxf(mx, __shfl_xor(mx, st, 64));
    }
    __shared__ float wmn[4], wmx[4];
    if (lane == 0) { wmn[wave] = mn; wmx[wave] = mx; }
    __syncthreads();
    if (t == 0) {
        pmin[bid] = fminf(fminf(wmn[0], wmn[1]), fminf(wmn[2], wmn[3]));
        pmax[bid] = fmaxf(fmaxf(wmx[0], wmx[1]), fmaxf(wmx[2], wmx[3]));
    }
}

// ---------------------------------------------------------------------------
// Kernel 2: the ENTIRE middle pipeline in one block of 1024 threads.
// Phase A: min/max finalize (32 images)
// Phase B: ballot histogram + cdf for 32 (b,g) pairs (4 wave-teams x 8 iters)
// Phase C: conv1 16->128 (5 taps) + depthwise conv2 (5 taps), ReLU
// Phase D: conv3 1x1 128->16 + softplus
// Phase E: cumsum + normalize + identity ramp -> lut[16][64]
// LDS ~52KB. Weights read via wave-uniform broadcast loads (no staging).
// ---------------------------------------------------------------------------
__global__ __launch_bounds__(1024) void k_mid(
        const float* __restrict__ pmin, const float* __restrict__ pmax,
        const float* __restrict__ blocksum,
        const float* __restrict__ w1, const float* __restrict__ b1,
        const float* __restrict__ w2, const float* __restrict__ b2,
        const float* __restrict__ w3, const float* __restrict__ b3,
        float* __restrict__ gmin, float* __restrict__ gmax,
        float* __restrict__ lut)
{
    const int t    = threadIdx.x;
    const int lane = t & 63;
    const int wave = t >> 6;   // 0..15

    __shared__ float s_mn[NIMG], s_inv[NIMG];
    __shared__ float pcdf_l[NIMG][NBINS];     // 8KB (scaled cdf per pair)
    __shared__ int   whist[4][4][NBINS];      // 4KB
    __shared__ float dcdf[GROUPS][NBINS];     // 4KB
    __shared__ float h1[HIDDEN][NBINS];       // 32KB
    __shared__ float sd[GROUPS][NBINS];       // 4KB

    // ---- Phase A: finalize per-image min/max (pair = t>>5, j = t&31) ----
    {
        const int pair = t >> 5, j = t & 31;
        float mn = pmin[pair * 32 + j];
        float mx = pmax[pair * 32 + j];
        #pragma unroll
        for (int st = 16; st > 0; st >>= 1) {   // reduce within 32-lane group
            mn = fminf(mn, __shfl_xor(mn, st, 64));
            mx = fmaxf(mx, __shfl_xor(mx, st, 64));
        }
        if (j == 0) {
            gmin[pair] = mn; gmax[pair] = mx;
            s_mn[pair] = mn; s_inv[pair] = 1.0f / (mx - mn + EPSF);
        }
    }
    __syncthreads();

    // ---- Phase B: histogram + cdf. team = wave>>2 handles pairs team*8+iter
    const int team = wave >> 2;   // 0..3
    const int q    = wave & 3;    // 0..3
    const int lt   = q * 64 + lane;  // 0..255 within team
    for (int iter = 0; iter < 8; ++iter) {
        const int bc = team * 8 + iter;
        const float mnv = s_mn[bc];
        const float inv = s_inv[bc];
        const float* bs = blocksum + bc * 1024;
        int idx[4];
        #pragma unroll
        for (int i = 0; i < 4; ++i) {
            float bmean = bs[lt + i * 256] * (1.0f / 1024.0f);
            float xs = (bmean - mnv) * inv;
            int id = (int)rintf(xs * 63.0f);   // round-half-even = jnp.round
            idx[i] = max(0, min(id, 63));
        }
        int cnt = 0;
        #pragma unroll 1
        for (int b = 0; b < NBINS; ++b) {
            int p = __popcll(__ballot(idx[0] == b)) + __popcll(__ballot(idx[1] == b))
                  + __popcll(__ballot(idx[2] == b)) + __popcll(__ballot(idx[3] == b));
            cnt += (lane == b) ? p : 0;
        }
        whist[team][q][lane] = cnt;
        __syncthreads();
        if (q == 0) {
            int h = whist[team][0][lane] + whist[team][1][lane]
                  + whist[team][2][lane] + whist[team][3][lane];
            #pragma unroll
            for (int d = 1; d < 64; d <<= 1) {
                int v = __shfl_up(h, d, 64);
                if (lane >= d) h += v;
            }
            pcdf_l[bc][lane] = (float)h * (0.5f / (1024.0f + EPSF)); // B-mean folded
        }
        __syncthreads();   // protect whist reuse next iter
    }

    // dcdf[g][k] = pcdf(b=0) + pcdf(b=1)   (t covers 16x64 exactly)
    dcdf[wave][lane] = pcdf_l[wave][lane] + pcdf_l[GROUPS + wave][lane];
    __syncthreads();

    // ---- Phase C: conv1 + conv2 fused, one channel row per wave-iteration --
    for (int i = 0; i < 8; ++i) {
        const int oc = i * 16 + wave;
        const int k  = lane;
        float acc = b1[oc];                       // wave-uniform broadcast
        const float* wp = w1 + (oc * GROUPS) * 25 + 10;   // kh=2 row
        for (int ic = 0; ic < GROUPS; ++ic) {
            const float* wrow = wp + ic * 25;
            #pragma unroll
            for (int tap = 0; tap < 5; ++tap) {
                const int kk = k - 2 + tap;
                if (kk >= 0 && kk < NBINS)
                    acc += wrow[tap] * dcdf[ic][kk];
            }
        }
        h1[oc][k] = fmaxf(acc, 0.f);
        // depthwise conv2: this wave just wrote the whole row oc; per-wave LDS
        // ops are in-order, so the 5 tap reads see the conv1 values.
        const float* w2p = w2 + oc * 25 + 10;
        float a = b2[oc];
        #pragma unroll
        for (int tap = 0; tap < 5; ++tap) {
            const int kk = k - 2 + tap;
            if (kk >= 0 && kk < NBINS)
                a += w2p[tap] * h1[oc][kk];
        }
        h1[oc][k] = fmaxf(a, 0.f);   // overwrite in place (reads issued above)
    }
    __syncthreads();

    // ---- Phase D: conv3 1x1 (128->16) + softplus; one output per thread ----
    {
        const int g = wave, k = lane;
        float acc = b3[g];
        const float* w3p = w3 + g * HIDDEN;       // wave-uniform broadcast
        for (int h = 0; h < HIDDEN; ++h)
            acc += w3p[h] * h1[h][k];
        sd[g][k] = fmaxf(acc, 0.f) + log1pf(expf(-fabsf(acc)));  // softplus
    }
    __syncthreads();

    // ---- Phase E: cumsum + normalize + identity ramp ----
    if (t < GROUPS) {
        float run = 0.f;
        for (int kk = 0; kk < NBINS; ++kk) { run += sd[t][kk]; sd[t][kk] = run; }
        const float invn = 1.0f / (run + EPSF);
        for (int kk = 0; kk < NBINS; ++kk)
            lut[t * NBINS + kk] = sd[t][kk] * invn + (float)kk * (1.0f / 63.0f);
    }
}

// ---------------------------------------------------------------------------
// Kernel 3: elementwise remap. grid = NIMG*64 blocks, 256 threads,
// 16 float4 per thread. LUT row (64 floats) in LDS. Output uses NONTEMPORAL
// stores (L3 bypass) so x (128MB) stays resident in the 256MB Infinity Cache.
// ---------------------------------------------------------------------------
__device__ __forceinline__ float remap1(float v, float mnv, float inv, float r,
                                        float aa, const float* lut_s)
{
    float x01 = (v - mnv) * inv;
    float pos = x01 * 63.0f;
    int il = (int)floorf(pos);
    il = max(0, min(il, 63));
    const int ih = min(il + 1, 63);
    const float w = pos - (float)il;
    const float vlo = lut_s[il];
    const float vhi = lut_s[ih];
    const float xe = fmaf(w, vhi - vlo, vlo);
    const float o01 = aa * xe + (1.0f - aa) * x01;
    return o01 * r + mnv;
}

__global__ __launch_bounds__(256) void k_apply(
        const float* __restrict__ x,
        const float* __restrict__ gmin, const float* __restrict__ gmax,
        const float* __restrict__ lut, const float* __restrict__ alpha,
        float* __restrict__ out)
{
    const int img  = blockIdx.x >> 6;
    const int part = blockIdx.x & 63;
    const int c    = img & 15;
    const int t    = threadIdx.x;

    __shared__ float lut_s[NBINS];
    if (t < NBINS) lut_s[t] = lut[c * NBINS + t];
    __syncthreads();

    const float mnv = gmin[img];
    const float mxv = gmax[img];
    const float r   = mxv - mnv;
    const float inv = 1.0f / (r + EPSF);
    const float aa  = 1.0f / (1.0f + expf(-alpha[0]));

    const size_t base4 = (size_t)img * (IMG_ELEMS / 4) + (size_t)part * 4096;
    const float4* xin = (const float4*)x;
    nfloat4* o4 = (nfloat4*)out;

    #pragma unroll 2
    for (int it = 0; it < 16; ++it) {
        const size_t f = base4 + (size_t)t + (size_t)it * 256;
        float4 v = xin[f];
        nfloat4 w;
        w.x = remap1(v.x, mnv, inv, r, aa, lut_s);
        w.y = remap1(v.y, mnv, inv, r, aa, lut_s);
        w.z = remap1(v.z, mnv, inv, r, aa, lut_s);
        w.w = remap1(v.w, mnv, inv, r, aa, lut_s);
        __builtin_nontemporal_store(w, &o4[f]);
    }
}

// ---------------------------------------------------------------------------
extern "C" void kernel_launch(void* const* d_in, const int* in_sizes, int n_in,
                              void* d_out, int out_size, void* d_ws, size_t ws_size,
                              hipStream_t stream)
{
    const float* x     = (const float*)d_in[0];
    const float* w1    = (const float*)d_in[1];
    const float* b1    = (const float*)d_in[2];
    const float* w2    = (const float*)d_in[3];
    const float* b2    = (const float*)d_in[4];
    const float* w3    = (const float*)d_in[5];
    const float* b3    = (const float*)d_in[6];
    const float* alpha = (const float*)d_in[7];
    float* out = (float*)d_out;

    float* ws = (float*)d_ws;
    float* blocksum = ws;            // 32768
    float* pmin     = ws + 32768;    // 1024
    float* pmax     = ws + 33792;    // 1024
    float* gmin     = ws + 34816;    // 32
    float* gmax     = ws + 34848;    // 32
    float* lut      = ws + 34880;    // 1024

    k_stats<<<NIMG * 32, 256,  0, stream>>>(x, blocksum, pmin, pmax);
    k_mid  <<<1,         1024, 0, stream>>>(pmin, pmax, blocksum,
                                            w1, b1, w2, b2, w3, b3,
                                            gmin, gmax, lut);
    k_apply<<<NIMG * 64, 256,  0, stream>>>(x, gmin, gmax, lut, alpha, out);
}

// Round 6
// 257.305 us; speedup vs baseline: 1.0080x; 1.0080x over previous
//
#include <hip/hip_runtime.h>
#include <math.h>

#define NBINS   64
#define GROUPS  16
#define HIDDEN  128
#define EPSF    1e-6f

// B=2, C=16, H=W=1024; 32 images of 1M floats; 32x32 tiles of 32x32 elems.
#define IMG_ELEMS   (1024*1024)
#define F4_PER_ROW  256          // 1024 cols / 4
#define NIMG        32           // B*C

typedef float nfloat4 __attribute__((ext_vector_type(4)));  // builtin-compatible

// ---------------------------------------------------------------------------
// Kernel 1: per image-row-chunk (32 rows): min/max partials + 32 tile sums.
// grid = NIMG*32 blocks, 256 threads.
// ---------------------------------------------------------------------------
__global__ __launch_bounds__(256) void k_stats(
        const float* __restrict__ x,
        float* __restrict__ blocksum,   // [NIMG][32][32] tile sums
        float* __restrict__ pmin,       // [NIMG*32]
        float* __restrict__ pmax)       // [NIMG*32]
{
    const int bid = blockIdx.x;
    const int bc  = bid >> 5;   // image
    const int i   = bid & 31;   // row-chunk (tile row)
    const int t   = threadIdx.x;
    const int lane = t & 63;
    const int wave = t >> 6;

    const float4* xin = (const float4*)(x + (size_t)bc * IMG_ELEMS);
    const int rowbase = (i * 32) * F4_PER_ROW;

    float s = 0.f, mn = INFINITY, mx = -INFINITY;
    #pragma unroll 4
    for (int r = 0; r < 32; ++r) {
        float4 v = xin[rowbase + r * F4_PER_ROW + t];
        s += (v.x + v.y) + (v.z + v.w);
        mn = fminf(mn, fminf(fminf(v.x, v.y), fminf(v.z, v.w)));
        mx = fmaxf(mx, fmaxf(fmaxf(v.x, v.y), fmaxf(v.z, v.w)));
    }

    // tile sums: 8 consecutive threads share tile j = t>>3 (within a wave)
    s += __shfl_xor(s, 4, 64);
    s += __shfl_xor(s, 2, 64);
    s += __shfl_xor(s, 1, 64);
    if ((t & 7) == 0)
        blocksum[bc * 1024 + i * 32 + (t >> 3)] = s;

    // block-wide min/max: wave shuffle reduce, then cross-wave via LDS
    #pragma unroll
    for (int st = 32; st > 0; st >>= 1) {
        mn = fminf(mn, __shfl_xor(mn, st, 64));
        mx = fmaxf(mx, __shfl_xor(mx, st, 64));
    }
    __shared__ float wmn[4], wmx[4];
    if (lane == 0) { wmn[wave] = mn; wmx[wave] = mx; }
    __syncthreads();
    if (t == 0) {
        pmin[bid] = fminf(fminf(wmn[0], wmn[1]), fminf(wmn[2], wmn[3]));
        pmax[bid] = fmaxf(fmaxf(wmx[0], wmx[1]), fmaxf(wmx[2], wmx[3]));
    }
}

// ---------------------------------------------------------------------------
// Kernel 2: the ENTIRE middle pipeline in one block of 1024 threads.
// Phase A: min/max finalize (32 images)
// Phase B: ballot histogram + cdf for 32 (b,g) pairs (4 wave-teams x 8 iters)
// Phase C: conv1 16->128 (5 taps) + depthwise conv2 (5 taps), ReLU
// Phase D: conv3 1x1 128->16 + softplus
// Phase E: cumsum + normalize + identity ramp -> lut[16][64]
// LDS ~52KB. Weights read via wave-uniform broadcast loads (no staging).
// ---------------------------------------------------------------------------
__global__ __launch_bounds__(1024) void k_mid(
        const float* __restrict__ pmin, const float* __restrict__ pmax,
        const float* __restrict__ blocksum,
        const float* __restrict__ w1, const float* __restrict__ b1,
        const float* __restrict__ w2, const float* __restrict__ b2,
        const float* __restrict__ w3, const float* __restrict__ b3,
        float* __restrict__ gmin, float* __restrict__ gmax,
        float* __restrict__ lut)
{
    const int t    = threadIdx.x;
    const int lane = t & 63;
    const int wave = t >> 6;   // 0..15

    __shared__ float s_mn[NIMG], s_inv[NIMG];
    __shared__ float pcdf_l[NIMG][NBINS];     // 8KB (scaled cdf per pair)
    __shared__ int   whist[4][4][NBINS];      // 4KB
    __shared__ float dcdf[GROUPS][NBINS];     // 4KB
    __shared__ float h1[HIDDEN][NBINS];       // 32KB
    __shared__ float sd[GROUPS][NBINS];       // 4KB

    // ---- Phase A: finalize per-image min/max (pair = t>>5, j = t&31) ----
    {
        const int pair = t >> 5, j = t & 31;
        float mn = pmin[pair * 32 + j];
        float mx = pmax[pair * 32 + j];
        #pragma unroll
        for (int st = 16; st > 0; st >>= 1) {   // reduce within 32-lane group
            mn = fminf(mn, __shfl_xor(mn, st, 64));
            mx = fmaxf(mx, __shfl_xor(mx, st, 64));
        }
        if (j == 0) {
            gmin[pair] = mn; gmax[pair] = mx;
            s_mn[pair] = mn; s_inv[pair] = 1.0f / (mx - mn + EPSF);
        }
    }
    __syncthreads();

    // ---- Phase B: histogram + cdf. team = wave>>2 handles pairs team*8+iter
    const int team = wave >> 2;   // 0..3
    const int q    = wave & 3;    // 0..3
    const int lt   = q * 64 + lane;  // 0..255 within team
    for (int iter = 0; iter < 8; ++iter) {
        const int bc = team * 8 + iter;
        const float mnv = s_mn[bc];
        const float inv = s_inv[bc];
        const float* bs = blocksum + bc * 1024;
        int idx[4];
        #pragma unroll
        for (int i = 0; i < 4; ++i) {
            float bmean = bs[lt + i * 256] * (1.0f / 1024.0f);
            float xs = (bmean - mnv) * inv;
            int id = (int)rintf(xs * 63.0f);   // round-half-even = jnp.round
            idx[i] = max(0, min(id, 63));
        }
        int cnt = 0;
        #pragma unroll 1
        for (int b = 0; b < NBINS; ++b) {
            int p = __popcll(__ballot(idx[0] == b)) + __popcll(__ballot(idx[1] == b))
                  + __popcll(__ballot(idx[2] == b)) + __popcll(__ballot(idx[3] == b));
            cnt += (lane == b) ? p : 0;
        }
        whist[team][q][lane] = cnt;
        __syncthreads();
        if (q == 0) {
            int h = whist[team][0][lane] + whist[team][1][lane]
                  + whist[team][2][lane] + whist[team][3][lane];
            #pragma unroll
            for (int d = 1; d < 64; d <<= 1) {
                int v = __shfl_up(h, d, 64);
                if (lane >= d) h += v;
            }
            pcdf_l[bc][lane] = (float)h * (0.5f / (1024.0f + EPSF)); // B-mean folded
        }
        __syncthreads();   // protect whist reuse next iter
    }

    // dcdf[g][k] = pcdf(b=0) + pcdf(b=1)   (t covers 16x64 exactly)
    dcdf[wave][lane] = pcdf_l[wave][lane] + pcdf_l[GROUPS + wave][lane];
    __syncthreads();

    // ---- Phase C: conv1 + conv2 fused, one channel row per wave-iteration --
    for (int i = 0; i < 8; ++i) {
        const int oc = i * 16 + wave;
        const int k  = lane;
        float acc = b1[oc];                       // wave-uniform broadcast
        const float* wp = w1 + (oc * GROUPS) * 25 + 10;   // kh=2 row
        for (int ic = 0; ic < GROUPS; ++ic) {
            const float* wrow = wp + ic * 25;
            #pragma unroll
            for (int tap = 0; tap < 5; ++tap) {
                const int kk = k - 2 + tap;
                if (kk >= 0 && kk < NBINS)
                    acc += wrow[tap] * dcdf[ic][kk];
            }
        }
        h1[oc][k] = fmaxf(acc, 0.f);
        // depthwise conv2: this wave just wrote the whole row oc; per-wave LDS
        // ops are in-order, so the 5 tap reads see the conv1 values.
        const float* w2p = w2 + oc * 25 + 10;
        float a = b2[oc];
        #pragma unroll
        for (int tap = 0; tap < 5; ++tap) {
            const int kk = k - 2 + tap;
            if (kk >= 0 && kk < NBINS)
                a += w2p[tap] * h1[oc][kk];
        }
        h1[oc][k] = fmaxf(a, 0.f);   // overwrite in place (reads issued above)
    }
    __syncthreads();

    // ---- Phase D: conv3 1x1 (128->16) + softplus; one output per thread ----
    {
        const int g = wave, k = lane;
        float acc = b3[g];
        const float* w3p = w3 + g * HIDDEN;       // wave-uniform broadcast
        for (int h = 0; h < HIDDEN; ++h)
            acc += w3p[h] * h1[h][k];
        sd[g][k] = fmaxf(acc, 0.f) + log1pf(expf(-fabsf(acc)));  // softplus
    }
    __syncthreads();

    // ---- Phase E: cumsum + normalize + identity ramp ----
    if (t < GROUPS) {
        float run = 0.f;
        for (int kk = 0; kk < NBINS; ++kk) { run += sd[t][kk]; sd[t][kk] = run; }
        const float invn = 1.0f / (run + EPSF);
        for (int kk = 0; kk < NBINS; ++kk)
            lut[t * NBINS + kk] = sd[t][kk] * invn + (float)kk * (1.0f / 63.0f);
    }
}

// ---------------------------------------------------------------------------
// Kernel 3: elementwise remap. grid = NIMG*64 blocks, 256 threads,
// 16 float4 per thread. LUT row (64 floats) in LDS. Output uses NONTEMPORAL
// stores (L3 bypass) so x (128MB) stays resident in the 256MB Infinity Cache.
// ---------------------------------------------------------------------------
__device__ __forceinline__ float remap1(float v, float mnv, float inv, float r,
                                        float aa, const float* lut_s)
{
    float x01 = (v - mnv) * inv;
    float pos = x01 * 63.0f;
    int il = (int)floorf(pos);
    il = max(0, min(il, 63));
    const int ih = min(il + 1, 63);
    const float w = pos - (float)il;
    const float vlo = lut_s[il];
    const float vhi = lut_s[ih];
    const float xe = fmaf(w, vhi - vlo, vlo);
    const float o01 = aa * xe + (1.0f - aa) * x01;
    return o01 * r + mnv;
}

__global__ __launch_bounds__(256) void k_apply(
        const float* __restrict__ x,
        const float* __restrict__ gmin, const float* __restrict__ gmax,
        const float* __restrict__ lut, const float* __restrict__ alpha,
        float* __restrict__ out)
{
    const int img  = blockIdx.x >> 6;
    const int part = blockIdx.x & 63;
    const int c    = img & 15;
    const int t    = threadIdx.x;

    __shared__ float lut_s[NBINS];
    if (t < NBINS) lut_s[t] = lut[c * NBINS + t];
    __syncthreads();

    const float mnv = gmin[img];
    const float mxv = gmax[img];
    const float r   = mxv - mnv;
    const float inv = 1.0f / (r + EPSF);
    const float aa  = 1.0f / (1.0f + expf(-alpha[0]));

    const size_t base4 = (size_t)img * (IMG_ELEMS / 4) + (size_t)part * 4096;
    const float4* xin = (const float4*)x;
    nfloat4* o4 = (nfloat4*)out;

    #pragma unroll 2
    for (int it = 0; it < 16; ++it) {
        const size_t f = base4 + (size_t)t + (size_t)it * 256;
        float4 v = xin[f];
        nfloat4 w;
        w.x = remap1(v.x, mnv, inv, r, aa, lut_s);
        w.y = remap1(v.y, mnv, inv, r, aa, lut_s);
        w.z = remap1(v.z, mnv, inv, r, aa, lut_s);
        w.w = remap1(v.w, mnv, inv, r, aa, lut_s);
        __builtin_nontemporal_store(w, &o4[f]);
    }
}

// ---------------------------------------------------------------------------
extern "C" void kernel_launch(void* const* d_in, const int* in_sizes, int n_in,
                              void* d_out, int out_size, void* d_ws, size_t ws_size,
                              hipStream_t stream)
{
    const float* x     = (const float*)d_in[0];
    const float* w1    = (const float*)d_in[1];
    const float* b1    = (const float*)d_in[2];
    const float* w2    = (const float*)d_in[3];
    const float* b2    = (const float*)d_in[4];
    const float* w3    = (const float*)d_in[5];
    const float* b3    = (const float*)d_in[6];
    const float* alpha = (const float*)d_in[7];
    float* out = (float*)d_out;

    float* ws = (float*)d_ws;
    float* blocksum = ws;            // 32768
    float* pmin     = ws + 32768;    // 1024
    float* pmax     = ws + 33792;    // 1024
    float* gmin     = ws + 34816;    // 32
    float* gmax     = ws + 34848;    // 32
    float* lut      = ws + 34880;    // 1024

    k_stats<<<NIMG * 32, 256,  0, stream>>>(x, blocksum, pmin, pmax);
    k_mid  <<<1,         1024, 0, stream>>>(pmin, pmax, blocksum,
                                            w1, b1, w2, b2, w3, b3,
                                            gmin, gmax, lut);
    k_apply<<<NIMG * 64, 256,  0, stream>>>(x, gmin, gmax, lut, alpha, out);
}

// Round 8
// 157.552 us; speedup vs baseline: 1.6462x; 1.6331x over previous
//
#include <hip/hip_runtime.h>
#include <math.h>

#define NBINS   64
#define GROUPS  16
#define HIDDEN  128
#define EPSF    1e-6f

// B=2, C=16, H=W=1024; 32 images of 1M floats; 32x32 tiles of 32x32 elems.
#define IMG_ELEMS   (1024*1024)
#define F4_PER_ROW  256          // 1024 cols / 4
#define NIMG        32           // B*C

typedef float nfloat4 __attribute__((ext_vector_type(4)));  // builtin-compatible

// ---------------------------------------------------------------------------
// Kernel 1: per image-row-chunk (32 rows): min/max partials + 32 tile sums.
// grid = NIMG*32 blocks, 256 threads.
// ---------------------------------------------------------------------------
__global__ __launch_bounds__(256) void k_stats(
        const float* __restrict__ x,
        float* __restrict__ blocksum,   // [NIMG][32][32] tile sums
        float* __restrict__ pmin,       // [NIMG*32]
        float* __restrict__ pmax)       // [NIMG*32]
{
    const int bid = blockIdx.x;
    const int bc  = bid >> 5;   // image
    const int i   = bid & 31;   // row-chunk (tile row)
    const int t   = threadIdx.x;
    const int lane = t & 63;
    const int wave = t >> 6;

    const float4* xin = (const float4*)(x + (size_t)bc * IMG_ELEMS);
    const int rowbase = (i * 32) * F4_PER_ROW;

    float s = 0.f, mn = INFINITY, mx = -INFINITY;
    #pragma unroll 4
    for (int r = 0; r < 32; ++r) {
        float4 v = xin[rowbase + r * F4_PER_ROW + t];
        s += (v.x + v.y) + (v.z + v.w);
        mn = fminf(mn, fminf(fminf(v.x, v.y), fminf(v.z, v.w)));
        mx = fmaxf(mx, fmaxf(fmaxf(v.x, v.y), fmaxf(v.z, v.w)));
    }

    // tile sums: 8 consecutive threads share tile j = t>>3 (within a wave)
    s += __shfl_xor(s, 4, 64);
    s += __shfl_xor(s, 2, 64);
    s += __shfl_xor(s, 1, 64);
    if ((t & 7) == 0)
        blocksum[bc * 1024 + i * 32 + (t >> 3)] = s;

    // block-wide min/max: wave shuffle reduce, then cross-wave via LDS
    #pragma unroll
    for (int st = 32; st > 0; st >>= 1) {
        mn = fminf(mn, __shfl_xor(mn, st, 64));
        mx = fmaxf(mx, __shfl_xor(mx, st, 64));
    }
    __shared__ float wmn[4], wmx[4];
    if (lane == 0) { wmn[wave] = mn; wmx[wave] = mx; }
    __syncthreads();
    if (t == 0) {
        pmin[bid] = fminf(fminf(wmn[0], wmn[1]), fminf(wmn[2], wmn[3]));
        pmax[bid] = fmaxf(fmaxf(wmx[0], wmx[1]), fmaxf(wmx[2], wmx[3]));
    }
}

// ---------------------------------------------------------------------------
// Kernel 2: entire middle pipeline, 1 block x 1024 threads, ALL weights
// staged into LDS cooperatively. Depthwise conv2 uses WAVE SHUFFLES (fixes
// R7: in-place LDS write->neighbor-read race under compiler reordering).
// LDS overlay (~53KB):
//   h1[128][64]  32KB   conv2 output (Phase C out, D in)
//   dcdf[16][64]  4KB   mean cdf (Phase B out, C in)
//   scratch[4096] 16KB  B: whist(0..1023 int) + pcdf_l(1024..3071)
//                       C: wchunk(0..2559) + w2s(2560..3199) + b1s/b2s/b3s(3200..3471)
//                       D: w3s(0..2047) + sd(2048..3071)   (b3s@3456 preserved)
// ---------------------------------------------------------------------------
__global__ __launch_bounds__(1024) void k_mid(
        const float* __restrict__ pmin, const float* __restrict__ pmax,
        const float* __restrict__ blocksum,
        const float* __restrict__ w1, const float* __restrict__ b1,
        const float* __restrict__ w2, const float* __restrict__ b2,
        const float* __restrict__ w3, const float* __restrict__ b3,
        float* __restrict__ gmin, float* __restrict__ gmax,
        float* __restrict__ lut)
{
    const int t    = threadIdx.x;
    const int lane = t & 63;
    const int wave = t >> 6;   // 0..15

    __shared__ float h1[HIDDEN][NBINS];
    __shared__ float dcdf[GROUPS][NBINS];
    __shared__ float scratch[4096];
    __shared__ float s_mn[NIMG], s_inv[NIMG];

    // ---- Phase A: finalize per-image min/max (pair = t>>5, j = t&31) ----
    {
        const int pair = t >> 5, j = t & 31;
        float mn = pmin[pair * 32 + j];
        float mx = pmax[pair * 32 + j];
        #pragma unroll
        for (int st = 16; st > 0; st >>= 1) {   // stays within 32-lane half
            mn = fminf(mn, __shfl_xor(mn, st, 64));
            mx = fmaxf(mx, __shfl_xor(mx, st, 64));
        }
        if (j == 0) {
            gmin[pair] = mn; gmax[pair] = mx;
            s_mn[pair] = mn; s_inv[pair] = 1.0f / (mx - mn + EPSF);
        }
    }
    __syncthreads();

    // ---- Phase B: ballot histogram + cdf; team = wave>>2 covers 8 pairs ----
    {
        int*   whist  = (int*)scratch;       // [4][4][64]
        float* pcdf_l = scratch + 1024;      // [32][64]
        const int team = wave >> 2;
        const int q    = wave & 3;
        const int lt   = q * 64 + lane;
        for (int iter = 0; iter < 8; ++iter) {
            const int bc = team * 8 + iter;
            const float mnv = s_mn[bc];
            const float inv = s_inv[bc];
            const float* bs = blocksum + bc * 1024;
            int idx[4];
            #pragma unroll
            for (int i = 0; i < 4; ++i) {
                float bmean = bs[lt + i * 256] * (1.0f / 1024.0f);
                float xs = (bmean - mnv) * inv;
                int id = (int)rintf(xs * 63.0f);   // round-half-even = jnp.round
                idx[i] = max(0, min(id, 63));
            }
            int cnt = 0;
            #pragma unroll 1
            for (int b = 0; b < NBINS; ++b) {
                int p = __popcll(__ballot(idx[0] == b)) + __popcll(__ballot(idx[1] == b))
                      + __popcll(__ballot(idx[2] == b)) + __popcll(__ballot(idx[3] == b));
                cnt += (lane == b) ? p : 0;
            }
            whist[(team * 4 + q) * 64 + lane] = cnt;
            __syncthreads();
            if (q == 0) {
                int h = whist[(team*4+0)*64+lane] + whist[(team*4+1)*64+lane]
                      + whist[(team*4+2)*64+lane] + whist[(team*4+3)*64+lane];
                #pragma unroll
                for (int d = 1; d < 64; d <<= 1) {
                    int v = __shfl_up(h, d, 64);
                    if (lane >= d) h += v;
                }
                pcdf_l[bc * 64 + lane] = (float)h * (0.5f / (1024.0f + EPSF));
            }
            __syncthreads();
        }
        // dcdf[g][k] = b0 + b1 halves (16x64 = 1024 threads, one each)
        dcdf[wave][lane] = pcdf_l[wave * 64 + lane] + pcdf_l[(GROUPS + wave) * 64 + lane];
    }
    __syncthreads();

    // ---- Phase C: conv1 (16->128, 5 taps) + depthwise conv2 via shuffles ---
    {
        float* wchunk = scratch;             // [32][80]
        float* w2s    = scratch + 2560;      // [128][5]
        float* b1s    = scratch + 3200;      // [128]
        float* b2s    = scratch + 3328;      // [128]
        float* b3s    = scratch + 3456;      // [16]  (used in Phase D)
        const int k = lane;
        for (int cc = 0; cc < 4; ++cc) {
            __syncthreads();   // prev chunk compute done (and Phase B reads done)
            for (int o = t; o < 32 * 80; o += 1024) {
                const int ocl = o / 80, rem = o % 80;
                const int ic = rem / 5, tap = rem % 5;
                wchunk[o] = w1[((cc * 32 + ocl) * GROUPS + ic) * 25 + 10 + tap];
            }
            if (cc == 0) {
                for (int o = t; o < 640; o += 1024)
                    w2s[o] = w2[(o / 5) * 25 + 10 + (o % 5)];
                if (t < 128)            b1s[t] = b1[t];
                else if (t < 256)       b2s[t - 128] = b2[t - 128];
                else if (t < 272)       b3s[t - 256] = b3[t - 256];
            }
            __syncthreads();
            #pragma unroll 2
            for (int r = 0; r < 2; ++r) {
                const int ocl = (wave << 1) | r;
                const int oc  = cc * 32 + ocl;
                float acc = b1s[oc];
                const float* wp = wchunk + ocl * 80;
                for (int ic = 0; ic < GROUPS; ++ic) {
                    #pragma unroll
                    for (int tap = 0; tap < 5; ++tap) {
                        const int kk = k - 2 + tap;
                        if (kk >= 0 && kk < NBINS)
                            acc += wp[ic * 5 + tap] * dcdf[ic][kk];
                    }
                }
                const float c1 = fmaxf(acc, 0.f);   // conv1[oc][k] in register
                // depthwise conv2: neighbor bins live in neighbor lanes of
                // THIS wave -> shuffle exchange, zero-guard = pad-0 border.
                const float m2 = __shfl_up(c1, 2, 64);
                const float m1 = __shfl_up(c1, 1, 64);
                const float p1 = __shfl_down(c1, 1, 64);
                const float p2 = __shfl_down(c1, 2, 64);
                const float* w2p = w2s + oc * 5;
                float a = b2s[oc];
                a += w2p[0] * ((k >= 2) ? m2 : 0.f);
                a += w2p[1] * ((k >= 1) ? m1 : 0.f);
                a += w2p[2] * c1;
                a += w2p[3] * ((k <= 62) ? p1 : 0.f);
                a += w2p[4] * ((k <= 61) ? p2 : 0.f);
                h1[oc][k] = fmaxf(a, 0.f);          // single write, no hazard
            }
        }
    }
    __syncthreads();

    // ---- Phase D: conv3 1x1 (128->16) + softplus ----
    {
        float* w3s = scratch;            // [16][128] (wchunk dead)
        float* sd  = scratch + 2048;     // [16][64]
        float* b3s = scratch + 3456;
        for (int o = t; o < GROUPS * HIDDEN; o += 1024) w3s[o] = w3[o];
        __syncthreads();
        const int g = wave, k = lane;
        float acc = b3s[g];
        const float* w3p = w3s + g * HIDDEN;
        #pragma unroll 8
        for (int h = 0; h < HIDDEN; ++h)
            acc += w3p[h] * h1[h][k];
        sd[g * 64 + k] = fmaxf(acc, 0.f) + log1pf(expf(-fabsf(acc)));
    }
    __syncthreads();

    // ---- Phase E: cumsum + normalize + identity ramp (reference order) ----
    if (t < GROUPS) {
        float* sd = scratch + 2048;
        float run = 0.f;
        for (int kk = 0; kk < NBINS; ++kk) { run += sd[t * 64 + kk]; sd[t * 64 + kk] = run; }
        const float invn = 1.0f / (run + EPSF);
        for (int kk = 0; kk < NBINS; ++kk)
            lut[t * NBINS + kk] = sd[t * 64 + kk] * invn + (float)kk * (1.0f / 63.0f);
    }
}

// ---------------------------------------------------------------------------
// Kernel 3: elementwise remap. grid = NIMG*64 blocks, 256 threads,
// 16 float4 per thread. LUT row (64 floats) in LDS. Nontemporal stores keep
// x L3-resident across kernels/replays.
// ---------------------------------------------------------------------------
__device__ __forceinline__ float remap1(float v, float mnv, float inv, float r,
                                        float aa, const float* lut_s)
{
    float x01 = (v - mnv) * inv;
    float pos = x01 * 63.0f;
    int il = (int)floorf(pos);
    il = max(0, min(il, 63));
    const int ih = min(il + 1, 63);
    const float w = pos - (float)il;
    const float vlo = lut_s[il];
    const float vhi = lut_s[ih];
    const float xe = fmaf(w, vhi - vlo, vlo);
    const float o01 = aa * xe + (1.0f - aa) * x01;
    return o01 * r + mnv;
}

__global__ __launch_bounds__(256) void k_apply(
        const float* __restrict__ x,
        const float* __restrict__ gmin, const float* __restrict__ gmax,
        const float* __restrict__ lut, const float* __restrict__ alpha,
        float* __restrict__ out)
{
    const int img  = blockIdx.x >> 6;
    const int part = blockIdx.x & 63;
    const int c    = img & 15;
    const int t    = threadIdx.x;

    __shared__ float lut_s[NBINS];
    if (t < NBINS) lut_s[t] = lut[c * NBINS + t];
    __syncthreads();

    const float mnv = gmin[img];
    const float mxv = gmax[img];
    const float r   = mxv - mnv;
    const float inv = 1.0f / (r + EPSF);
    const float aa  = 1.0f / (1.0f + expf(-alpha[0]));

    const size_t base4 = (size_t)img * (IMG_ELEMS / 4) + (size_t)part * 4096;
    const float4* xin = (const float4*)x;
    nfloat4* o4 = (nfloat4*)out;

    #pragma unroll 2
    for (int it = 0; it < 16; ++it) {
        const size_t f = base4 + (size_t)t + (size_t)it * 256;
        float4 v = xin[f];
        nfloat4 w;
        w.x = remap1(v.x, mnv, inv, r, aa, lut_s);
        w.y = remap1(v.y, mnv, inv, r, aa, lut_s);
        w.z = remap1(v.z, mnv, inv, r, aa, lut_s);
        w.w = remap1(v.w, mnv, inv, r, aa, lut_s);
        __builtin_nontemporal_store(w, &o4[f]);
    }
}

// ---------------------------------------------------------------------------
extern "C" void kernel_launch(void* const* d_in, const int* in_sizes, int n_in,
                              void* d_out, int out_size, void* d_ws, size_t ws_size,
                              hipStream_t stream)
{
    const float* x     = (const float*)d_in[0];
    const float* w1    = (const float*)d_in[1];
    const float* b1    = (const float*)d_in[2];
    const float* w2    = (const float*)d_in[3];
    const float* b2    = (const float*)d_in[4];
    const float* w3    = (const float*)d_in[5];
    const float* b3    = (const float*)d_in[6];
    const float* alpha = (const float*)d_in[7];
    float* out = (float*)d_out;

    float* ws = (float*)d_ws;
    float* blocksum = ws;            // 32768
    float* pmin     = ws + 32768;    // 1024
    float* pmax     = ws + 33792;    // 1024
    float* gmin     = ws + 34816;    // 32
    float* gmax     = ws + 34848;    // 32
    float* lut      = ws + 34880;    // 1024

    k_stats<<<NIMG * 32, 256,  0, stream>>>(x, blocksum, pmin, pmax);
    k_mid  <<<1,         1024, 0, stream>>>(pmin, pmax, blocksum,
                                            w1, b1, w2, b2, w3, b3,
                                            gmin, gmax, lut);
    k_apply<<<NIMG * 64, 256,  0, stream>>>(x, gmin, gmax, lut, alpha, out);
}

// Round 9
// 81.932 us; speedup vs baseline: 3.1656x; 1.9230x over previous
//
#include <hip/hip_runtime.h>
#include <math.h>

#define NBINS   64
#define GROUPS  16
#define HIDDEN  128
#define EPSF    1e-6f

// B=2, C=16, H=W=1024; 32 images of 1M floats; 32x32 tiles of 32x32 elems.
#define IMG_ELEMS   (1024*1024)
#define F4_PER_ROW  256          // 1024 cols / 4
#define NIMG        32           // B*C

typedef float nfloat4 __attribute__((ext_vector_type(4)));  // builtin-compatible

// ---------------------------------------------------------------------------
// Kernel 1: per image-row-chunk (32 rows): min/max partials + 32 tile sums.
// grid = NIMG*32 blocks, 256 threads.
// ---------------------------------------------------------------------------
__global__ __launch_bounds__(256) void k_stats(
        const float* __restrict__ x,
        float* __restrict__ blocksum,   // [NIMG][32][32] tile sums
        float* __restrict__ pmin,       // [NIMG*32]
        float* __restrict__ pmax)       // [NIMG*32]
{
    const int bid = blockIdx.x;
    const int bc  = bid >> 5;   // image
    const int i   = bid & 31;   // row-chunk (tile row)
    const int t   = threadIdx.x;
    const int lane = t & 63;
    const int wave = t >> 6;

    const float4* xin = (const float4*)(x + (size_t)bc * IMG_ELEMS);
    const int rowbase = (i * 32) * F4_PER_ROW;

    float s = 0.f, mn = INFINITY, mx = -INFINITY;
    #pragma unroll 4
    for (int r = 0; r < 32; ++r) {
        float4 v = xin[rowbase + r * F4_PER_ROW + t];
        s += (v.x + v.y) + (v.z + v.w);
        mn = fminf(mn, fminf(fminf(v.x, v.y), fminf(v.z, v.w)));
        mx = fmaxf(mx, fmaxf(fmaxf(v.x, v.y), fmaxf(v.z, v.w)));
    }

    // tile sums: 8 consecutive threads share tile j = t>>3 (within a wave)
    s += __shfl_xor(s, 4, 64);
    s += __shfl_xor(s, 2, 64);
    s += __shfl_xor(s, 1, 64);
    if ((t & 7) == 0)
        blocksum[bc * 1024 + i * 32 + (t >> 3)] = s;

    // block-wide min/max: wave shuffle reduce, then cross-wave via LDS
    #pragma unroll
    for (int st = 32; st > 0; st >>= 1) {
        mn = fminf(mn, __shfl_xor(mn, st, 64));
        mx = fmaxf(mx, __shfl_xor(mx, st, 64));
    }
    __shared__ float wmn[4], wmx[4];
    if (lane == 0) { wmn[wave] = mn; wmx[wave] = mx; }
    __syncthreads();
    if (t == 0) {
        pmin[bid] = fminf(fminf(wmn[0], wmn[1]), fminf(wmn[2], wmn[3]));
        pmax[bid] = fmaxf(fmaxf(wmx[0], wmx[1]), fmaxf(wmx[2], wmx[3]));
    }
}

// ---------------------------------------------------------------------------
// Kernel 2: fused per-image min/max finalize + histogram via wave ballots
// (no atomics) -> scaled cdf. grid = 32 blocks (bc = b*16+g), 256 threads.
// ---------------------------------------------------------------------------
__global__ __launch_bounds__(256) void k_hist(
        const float* __restrict__ pmin, const float* __restrict__ pmax,
        const float* __restrict__ blocksum,
        float* __restrict__ gmin, float* __restrict__ gmax,
        float* __restrict__ pcdf)       // [2][16][64]
{
    const int bc   = blockIdx.x;
    const int t    = threadIdx.x;
    const int lane = t & 63;
    const int wave = t >> 6;

    __shared__ float s_mn, s_inv;
    if (wave == 0) {
        float mn = (lane < 32) ? pmin[bc * 32 + lane] : INFINITY;
        float mx = (lane < 32) ? pmax[bc * 32 + lane] : -INFINITY;
        #pragma unroll
        for (int st = 32; st > 0; st >>= 1) {
            mn = fminf(mn, __shfl_xor(mn, st, 64));
            mx = fmaxf(mx, __shfl_xor(mx, st, 64));
        }
        if (lane == 0) {
            gmin[bc] = mn; gmax[bc] = mx;
            s_mn = mn; s_inv = 1.0f / (mx - mn + EPSF);
        }
    }
    __syncthreads();
    const float mnv = s_mn;
    const float inv = s_inv;

    int idx0, idx1, idx2, idx3;
    {
        const float* bs = blocksum + bc * 1024;
        #define MKIDX(D, IT) { \
            float bmean = bs[t + (IT)*256] * (1.0f / 1024.0f); \
            float xs = (bmean - mnv) * inv; \
            int id = (int)rintf(xs * 63.0f); \
            D = max(0, min(id, 63)); }
        MKIDX(idx0, 0) MKIDX(idx1, 1) MKIDX(idx2, 2) MKIDX(idx3, 3)
        #undef MKIDX
    }

    // lane l accumulates count of bin l within this wave
    int cnt = 0;
    #pragma unroll 1
    for (int b = 0; b < NBINS; ++b) {
        unsigned long long m0 = __ballot(idx0 == b);
        unsigned long long m1 = __ballot(idx1 == b);
        unsigned long long m2 = __ballot(idx2 == b);
        unsigned long long m3 = __ballot(idx3 == b);
        int p = __popcll(m0) + __popcll(m1) + __popcll(m2) + __popcll(m3);
        cnt += (lane == b) ? p : 0;
    }

    __shared__ int whist[4][NBINS];
    whist[wave][lane] = cnt;
    __syncthreads();

    if (t < NBINS) {
        int h = whist[0][t] + whist[1][t] + whist[2][t] + whist[3][t];
        // inclusive scan over 64 bins (lane == bin)
        #pragma unroll
        for (int d = 1; d < 64; d <<= 1) {
            int v = __shfl_up(h, d, 64);
            if (t >= d) h += v;
        }
        const float scale = 0.5f / (1024.0f + EPSF);   // mean over B pre-applied
        pcdf[bc * NBINS + t] = (float)h * scale;
    }
}

// ---------------------------------------------------------------------------
// Kernel 3: conv1 (16->128ch, 5 taps, ReLU) + depthwise conv2 via WAVE
// SHUFFLES (race-free). grid = 32 blocks x 4 channels; 256 thr = 4ch x 64bins.
// ---------------------------------------------------------------------------
__global__ __launch_bounds__(256) void k_conv12(
        const float* __restrict__ pcdf,
        const float* __restrict__ w1, const float* __restrict__ b1,
        const float* __restrict__ w2, const float* __restrict__ b2,
        float* __restrict__ h2)         // [128][64]
{
    __shared__ float dcdf[GROUPS][NBINS];
    __shared__ float w1s[4 * GROUPS * 5];
    __shared__ float w2s[4][5];

    const int t   = threadIdx.x;
    const int ocb = blockIdx.x * 4;
    const int ocl = t >> 6;              // wave-uniform
    const int k   = t & 63;

    // dcdf = sum of the two pre-scaled b-halves
    for (int o = t; o < GROUPS * NBINS; o += 256)
        ((float*)dcdf)[o] = pcdf[o] + pcdf[GROUPS * NBINS + o];

    // conv1 weights, kh=2 row only: [ocl][ic][tap]
    for (int o = t; o < 4 * GROUPS * 5; o += 256) {
        const int oo  = o / 80;
        const int rem = o - oo * 80;
        const int ic  = rem / 5;
        const int tap = rem - ic * 5;
        w1s[o] = w1[((ocb + oo) * GROUPS + ic) * 25 + 10 + tap];
    }
    if (t < 20) w2s[t / 5][t % 5] = w2[(ocb + t / 5) * 25 + 10 + t % 5];
    __syncthreads();

    // conv1: 80 MACs per thread
    float acc = b1[ocb + ocl];
    const float* wrow = w1s + ocl * 80;
    for (int ic = 0; ic < GROUPS; ++ic) {
        #pragma unroll
        for (int tap = 0; tap < 5; ++tap) {
            const int kk = k - 2 + tap;
            if (kk >= 0 && kk < NBINS)
                acc += wrow[ic * 5 + tap] * dcdf[ic][kk];
        }
    }
    const float c1 = fmaxf(acc, 0.f);

    // depthwise conv2: neighbor bins are neighbor lanes -> shuffles,
    // zero-guards implement the pad-0 border. No LDS hazard possible.
    const float m2 = __shfl_up(c1, 2, 64);
    const float m1 = __shfl_up(c1, 1, 64);
    const float p1 = __shfl_down(c1, 1, 64);
    const float p2 = __shfl_down(c1, 2, 64);
    float a = b2[ocb + ocl];
    a += w2s[ocl][0] * ((k >= 2) ? m2 : 0.f);
    a += w2s[ocl][1] * ((k >= 1) ? m1 : 0.f);
    a += w2s[ocl][2] * c1;
    a += w2s[ocl][3] * ((k <= 62) ? p1 : 0.f);
    a += w2s[ocl][4] * ((k <= 61) ? p2 : 0.f);
    h2[(ocb + ocl) * NBINS + k] = fmaxf(a, 0.f);
}

// ---------------------------------------------------------------------------
// Kernel 4: fused lut-finalize + elementwise remap. grid = NIMG*64 blocks,
// 256 threads. Each block needs only ONE lut row (group g == channel c since
// C/G == 1): conv3 for g (4 waves x 32-MAC partials over L2-resident h2),
// softplus, 64-lane shuffle-scan cumsum, normalize + ramp -> LDS; then stream
// 16 float4/thread with nontemporal stores (keeps x L3-resident).
// ---------------------------------------------------------------------------
__global__ __launch_bounds__(256) void k_apply(
        const float* __restrict__ x,
        const float* __restrict__ gmin, const float* __restrict__ gmax,
        const float* __restrict__ h2,
        const float* __restrict__ w3, const float* __restrict__ b3,
        const float* __restrict__ alpha,
        float* __restrict__ out)
{
    const int img  = blockIdx.x >> 6;
    const int part = blockIdx.x & 63;
    const int c    = img & 15;         // channel == group (C/G == 1)
    const int t    = threadIdx.x;
    const int q    = t >> 6;           // wave 0..3
    const int k    = t & 63;

    __shared__ float partial[4][NBINS];
    __shared__ float lut_s[NBINS];

    // conv3 partial: wave q covers h = q*32 .. q*32+31
    {
        float part_acc = 0.f;
        const float* w3p = w3 + c * HIDDEN + q * 32;   // wave-uniform reads
        const float* h2p = h2 + (q * 32) * NBINS + k;  // coalesced per h
        #pragma unroll 8
        for (int h = 0; h < 32; ++h)
            part_acc += w3p[h] * h2p[h * NBINS];
        partial[q][k] = part_acc;
    }
    __syncthreads();
    if (q == 0) {
        float acc = b3[c] + ((partial[0][k] + partial[1][k])
                           + (partial[2][k] + partial[3][k]));
        float d = fmaxf(acc, 0.f) + log1pf(expf(-fabsf(acc)));  // softplus
        // inclusive scan over 64 bins (lane == bin)
        #pragma unroll
        for (int dd = 1; dd < 64; dd <<= 1) {
            float v = __shfl_up(d, dd, 64);
            if (k >= dd) d += v;
        }
        const float tot = __shfl(d, 63, 64);
        lut_s[k] = d / (tot + EPSF) + (float)k * (1.0f / 63.0f);
    }
    __syncthreads();

    const float mnv = gmin[img];
    const float mxv = gmax[img];
    const float r   = mxv - mnv;
    const float inv = 1.0f / (r + EPSF);
    const float aa  = 1.0f / (1.0f + expf(-alpha[0]));

    const size_t base4 = (size_t)img * (IMG_ELEMS / 4) + (size_t)part * 4096;
    const float4* xin = (const float4*)x;
    nfloat4* o4 = (nfloat4*)out;

    #pragma unroll 2
    for (int it = 0; it < 16; ++it) {
        const size_t f = base4 + (size_t)t + (size_t)it * 256;
        float4 v = xin[f];
        nfloat4 w;
        {
            float x01 = (v.x - mnv) * inv;
            float pos = x01 * 63.0f;
            int il = max(0, min((int)floorf(pos), 63));
            int ih = min(il + 1, 63);
            float wt = pos - (float)il;
            float vlo = lut_s[il], vhi = lut_s[ih];
            w.x = (aa * fmaf(wt, vhi - vlo, vlo) + (1.0f - aa) * x01) * r + mnv;
        }
        {
            float x01 = (v.y - mnv) * inv;
            float pos = x01 * 63.0f;
            int il = max(0, min((int)floorf(pos), 63));
            int ih = min(il + 1, 63);
            float wt = pos - (float)il;
            float vlo = lut_s[il], vhi = lut_s[ih];
            w.y = (aa * fmaf(wt, vhi - vlo, vlo) + (1.0f - aa) * x01) * r + mnv;
        }
        {
            float x01 = (v.z - mnv) * inv;
            float pos = x01 * 63.0f;
            int il = max(0, min((int)floorf(pos), 63));
            int ih = min(il + 1, 63);
            float wt = pos - (float)il;
            float vlo = lut_s[il], vhi = lut_s[ih];
            w.z = (aa * fmaf(wt, vhi - vlo, vlo) + (1.0f - aa) * x01) * r + mnv;
        }
        {
            float x01 = (v.w - mnv) * inv;
            float pos = x01 * 63.0f;
            int il = max(0, min((int)floorf(pos), 63));
            int ih = min(il + 1, 63);
            float wt = pos - (float)il;
            float vlo = lut_s[il], vhi = lut_s[ih];
            w.w = (aa * fmaf(wt, vhi - vlo, vlo) + (1.0f - aa) * x01) * r + mnv;
        }
        __builtin_nontemporal_store(w, &o4[f]);
    }
}

// ---------------------------------------------------------------------------
extern "C" void kernel_launch(void* const* d_in, const int* in_sizes, int n_in,
                              void* d_out, int out_size, void* d_ws, size_t ws_size,
                              hipStream_t stream)
{
    const float* x     = (const float*)d_in[0];
    const float* w1    = (const float*)d_in[1];
    const float* b1    = (const float*)d_in[2];
    const float* w2    = (const float*)d_in[3];
    const float* b2    = (const float*)d_in[4];
    const float* w3    = (const float*)d_in[5];
    const float* b3    = (const float*)d_in[6];
    const float* alpha = (const float*)d_in[7];
    float* out = (float*)d_out;

    float* ws = (float*)d_ws;
    float* blocksum = ws;            // 32768
    float* pmin     = ws + 32768;    // 1024
    float* pmax     = ws + 33792;    // 1024
    float* gmin     = ws + 34816;    // 32
    float* gmax     = ws + 34848;    // 32
    float* pcdf     = ws + 34880;    // 2048
    float* h2       = ws + 36928;    // 8192

    k_stats <<<NIMG * 32, 256, 0, stream>>>(x, blocksum, pmin, pmax);
    k_hist  <<<NIMG,      256, 0, stream>>>(pmin, pmax, blocksum, gmin, gmax, pcdf);
    k_conv12<<<32,        256, 0, stream>>>(pcdf, w1, b1, w2, b2, h2);
    k_apply <<<NIMG * 64, 256, 0, stream>>>(x, gmin, gmax, h2, w3, b3, alpha, out);
}